// Round 5
// baseline (837.640 us; speedup 1.0000x reference)
//
#include <hip/hip_runtime.h>
#include <hip/hip_fp16.h>
#include <math.h>

#define D 128
#define SCAN_CHUNK 1024
#define SH 13              // coarse bucket shift: 8192 dsts per bucket
#define BW (1 << SH)

typedef _Float16 half4v __attribute__((ext_vector_type(4)));
typedef _Float16 half8  __attribute__((ext_vector_type(8)));
typedef float    floatx16 __attribute__((ext_vector_type(16)));

// ---------------------------------------------------------------------------
// Cast fp32 -> fp16 (4 elems/thread).
// ---------------------------------------------------------------------------
__global__ __launch_bounds__(256) void cast_half(
        const float* __restrict__ x, _Float16* __restrict__ y, int n) {
    int i = blockIdx.x * 256 + threadIdx.x;
    int idx = i * 4;
    if (idx >= n) return;
    float4 v = *(const float4*)(x + idx);
    half4v h;
    h[0] = (_Float16)v.x; h[1] = (_Float16)v.y;
    h[2] = (_Float16)v.z; h[3] = (_Float16)v.w;
    *(half4v*)(y + idx) = h;
}

// ---------------------------------------------------------------------------
// Build B fragments pre-swizzled for v_mfma_f32_32x32x16_f16.
// WT[k][c] = (k<128) ? w_l[c][k] : w_r[c][k-128], k in [0,256).
// Fragment f = ks*4+cb, lane l, elem j:
//   value = WT[ks*16 + (l>>5)*8 + j][cb*32 + (l&31)] at B[f*512 + l*8 + j].
// ---------------------------------------------------------------------------
__global__ __launch_bounds__(256) void prep_bswz(
        const float* __restrict__ wl, const float* __restrict__ wr,
        _Float16* __restrict__ B) {
    int idx = blockIdx.x * 256 + threadIdx.x;  // 64*512 = 32768
    if (idx >= 64 * 512) return;
    int j = idx & 7;
    int lane = (idx >> 3) & 63;
    int f = idx >> 9;
    int ks = f >> 2, cb = f & 3;
    int k = ks * 16 + (lane >> 5) * 8 + j;
    int c = cb * 32 + (lane & 31);
    float v = (k < 128) ? wl[c * 128 + k] : wr[c * 128 + (k - 128)];
    B[idx] = (_Float16)v;
}

// ---------------------------------------------------------------------------
// Fused histogram for both graphs: counts of dst into cnt0/cnt1 (pre-zeroed).
// ---------------------------------------------------------------------------
__global__ __launch_bounds__(256) void hist2(
        const int* __restrict__ ei0, const int* __restrict__ ei1, int E,
        int* __restrict__ cnt0, int* __restrict__ cnt1) {
    int t = blockIdx.x * 256 + threadIdx.x;
    if (t >= 2 * E) return;
    int g = t >= E;
    int e = t - g * E;
    const int* ei = g ? ei1 : ei0;
    int* cnt = g ? cnt1 : cnt0;
    atomicAdd(&cnt[ei[E + e]], 1);
}

// ---------------------------------------------------------------------------
// Device-wide exclusive scan over both count arrays, 3 fused phases.
// blk_sums half g occupies [g*256, g*256+nb).
// ---------------------------------------------------------------------------
__global__ __launch_bounds__(256) void scan_phase_a(
        const int* __restrict__ cnt0, const int* __restrict__ cnt1,
        int N, int nb, int* __restrict__ blk_sums) {
    __shared__ int red[256];
    int t = threadIdx.x;
    int g = blockIdx.x >= nb;
    int bi = blockIdx.x - g * nb;
    const int* counts = g ? cnt1 : cnt0;
    int base = bi * SCAN_CHUNK + t * 4;
    int s = 0;
#pragma unroll
    for (int i = 0; i < 4; ++i) {
        int idx = base + i;
        if (idx < N) s += counts[idx];
    }
    red[t] = s;
    __syncthreads();
    for (int off = 128; off > 0; off >>= 1) {
        if (t < off) red[t] += red[t + off];
        __syncthreads();
    }
    if (t == 0) blk_sums[g * 256 + bi] = red[0];
}

__global__ __launch_bounds__(256) void scan_phase_b(
        int* __restrict__ blk_sums, int nb) {
    __shared__ int part[256];
    int t = threadIdx.x;
    int* bs = blk_sums + blockIdx.x * 256;
    part[t] = (t < nb) ? bs[t] : 0;
    __syncthreads();
    for (int off = 1; off < 256; off <<= 1) {
        int u = (t >= off) ? part[t - off] : 0;
        __syncthreads();
        part[t] += u;
        __syncthreads();
    }
    if (t < nb) bs[t] = (t == 0) ? 0 : part[t - 1];
}

__global__ __launch_bounds__(256) void scan_phase_c(
        const int* __restrict__ cnt0, const int* __restrict__ cnt1,
        int N, int E, int nb, const int* __restrict__ blk_sums,
        int* __restrict__ rp0, int* __restrict__ rp1) {
    __shared__ int part[256];
    int t = threadIdx.x;
    int g = blockIdx.x >= nb;
    int bi = blockIdx.x - g * nb;
    const int* counts = g ? cnt1 : cnt0;
    int* row_ptr = g ? rp1 : rp0;
    int base = bi * SCAN_CHUNK + t * 4;
    int c[4];
    int s = 0;
#pragma unroll
    for (int i = 0; i < 4; ++i) {
        int idx = base + i;
        c[i] = (idx < N) ? counts[idx] : 0;
        s += c[i];
    }
    part[t] = s;
    __syncthreads();
    for (int off = 1; off < 256; off <<= 1) {
        int u = (t >= off) ? part[t - off] : 0;
        __syncthreads();
        part[t] += u;
        __syncthreads();
    }
    int run = blk_sums[g * 256 + bi] + ((t == 0) ? 0 : part[t - 1]);
#pragma unroll
    for (int i = 0; i < 4; ++i) {
        int idx = base + i;
        if (idx < N) {
            row_ptr[idx] = run;
            run += c[i];
        }
    }
    if (bi == 0 && t == 0) row_ptr[N] = E;
}

// ---------------------------------------------------------------------------
// Init coarse-bucket global cursors (line-padded: gcur[idx*16]) from row_ptr.
// idx = g*16 + b; base = row_ptr_g[min(b<<SH, N)].
// ---------------------------------------------------------------------------
__global__ void gcur_init(const int* __restrict__ rp0,
                          const int* __restrict__ rp1,
                          int N, int* __restrict__ gcur) {
    int t = threadIdx.x;
    if (t >= 32) return;
    int g = t >> 4;
    int b = t & 15;
    const int* rp = g ? rp1 : rp0;
    int lo = b << SH;
    if (lo > N) lo = N;
    gcur[t * 16] = rp[lo];
}

// ---------------------------------------------------------------------------
// Multisplit pass 1: bin edges of both graphs into 16 coarse buckets each.
// Wave-level peer matching + block-level LDS aggregation -> one global
// atomic reserve per (block,bucket); lanes write packed (src | dstlow<<17)
// into stage at coarse-grouped final layout (base row_ptr[b<<SH], exact fit).
// ---------------------------------------------------------------------------
__global__ __launch_bounds__(256) void bin_pass1(
        const int* __restrict__ ei0, const int* __restrict__ ei1, int E,
        int* __restrict__ gcur,
        int* __restrict__ stage0, int* __restrict__ stage1) {
    __shared__ int cnt_lds[32];
    __shared__ int base_lds[32];
    int t = blockIdx.x * 256 + threadIdx.x;
    int lane = threadIdx.x & 63;
    bool valid = t < 2 * E;
    int g = 0, src = 0, dst = 0, idx = 32;
    if (valid) {
        g = t >= E;
        int e = t - g * E;
        const int* ei = g ? ei1 : ei0;
        src = ei[e];
        dst = ei[E + e];
        idx = g * 16 + (dst >> SH);
    }
    if (threadIdx.x < 32) cnt_lds[threadIdx.x] = 0;
    __syncthreads();

    unsigned long long peers = 0;
#pragma unroll
    for (int k = 0; k < 32; ++k) {
        unsigned long long m = __ballot(idx == k);
        if (idx == k) peers = m;
    }
    int wbase = 0;
    if (valid) {
        int leader = __ffsll(peers) - 1;
        int np = __popcll(peers);
        if (lane == leader) wbase = atomicAdd(&cnt_lds[idx], np);
        wbase = __shfl(wbase, leader);
    }
    __syncthreads();
    if (threadIdx.x < 32 && cnt_lds[threadIdx.x] > 0)
        base_lds[threadIdx.x] =
            atomicAdd(&gcur[threadIdx.x * 16], cnt_lds[threadIdx.x]);
    __syncthreads();
    if (valid) {
        int rank = __popcll(peers & ((1ull << lane) - 1ull));
        int pos = base_lds[idx] + wbase + rank;
        int* stage = g ? stage1 : stage0;
        stage[pos] = src | ((dst & (BW - 1)) << 17);
    }
}

// ---------------------------------------------------------------------------
// Multisplit pass 2: one block per coarse bucket; LDS per-dst cursors from
// row_ptr; scatter srcs to final CSR slots. All writes land in this bucket's
// ~512 KB region from ONE block (one XCD) -> L2 merges to full lines.
// ---------------------------------------------------------------------------
__global__ __launch_bounds__(256) void bin_pass2(
        const int* __restrict__ rp0, const int* __restrict__ rp1,
        const int* __restrict__ stage0, const int* __restrict__ stage1,
        int* __restrict__ es0, int* __restrict__ es1, int N, int NB) {
    __shared__ int cur[BW];
    int gb = blockIdx.x;
    int g = gb >= NB;
    int b = gb - g * NB;
    const int* rp = g ? rp1 : rp0;
    const int* stage = g ? stage1 : stage0;
    int* es = g ? es1 : es0;
    int lo = b << SH;
    int hi = min(lo + BW, N);
    int nd = hi - lo;
    for (int d = threadIdx.x; d < nd; d += 256) cur[d] = rp[lo + d];
    __syncthreads();
    int beg = rp[lo], end = rp[hi];
    int i = beg + threadIdx.x;
    for (; i + 768 < end; i += 1024) {
        unsigned p0 = (unsigned)stage[i];
        unsigned p1 = (unsigned)stage[i + 256];
        unsigned p2 = (unsigned)stage[i + 512];
        unsigned p3 = (unsigned)stage[i + 768];
        int q0 = atomicAdd(&cur[p0 >> 17], 1);
        int q1 = atomicAdd(&cur[p1 >> 17], 1);
        int q2 = atomicAdd(&cur[p2 >> 17], 1);
        int q3 = atomicAdd(&cur[p3 >> 17], 1);
        es[q0] = p0 & 0x1FFFF;
        es[q1] = p1 & 0x1FFFF;
        es[q2] = p2 & 0x1FFFF;
        es[q3] = p3 & 0x1FFFF;
    }
    for (; i < end; i += 256) {
        unsigned p = (unsigned)stage[i];
        int q = atomicAdd(&cur[p >> 17], 1);
        es[q] = p & 0x1FFFF;
    }
}

// ---------------------------------------------------------------------------
// Gather aggregation in fp16: one wave per node, lane holds a half2 (2 dims).
// 8-deep MLP unroll; fp32 accumulation, fp16 output.
// ---------------------------------------------------------------------------
__global__ __launch_bounds__(256) void agg_half(
        const _Float16* __restrict__ x, const int* __restrict__ row_ptr,
        const int* __restrict__ edge_src, _Float16* __restrict__ agg, int N) {
    int gt = blockIdx.x * 256 + threadIdx.x;
    int w = gt >> 6;
    int lane = gt & 63;
    if (w >= N) return;
    int beg = row_ptr[w];
    int end = row_ptr[w + 1];
    const __half2* base = (const __half2*)x + lane;
    float ax = 0.0f, ay = 0.0f;
    int e = beg;
    for (; e + 8 <= end; e += 8) {
        int s[8];
#pragma unroll
        for (int j = 0; j < 8; ++j) s[j] = edge_src[e + j];
#pragma unroll
        for (int j = 0; j < 8; ++j) {
            float2 f = __half22float2(base[(size_t)s[j] * 64]);
            ax += f.x;
            ay += f.y;
        }
    }
    for (; e < end; ++e) {
        float2 f = __half22float2(base[(size_t)edge_src[e] * 64]);
        ax += f.x;
        ay += f.y;
    }
    int deg = end - beg;
    float inv = (deg > 0) ? 1.0f / (float)deg : 0.0f;
    ((__half2*)agg)[(size_t)w * 64 + lane] =
        __float22half2_rn(make_float2(ax * inv, ay * inv));
}

// ---------------------------------------------------------------------------
// MFMA SAGE linear (unchanged from round 4).
// ---------------------------------------------------------------------------
template <bool GELU, typename OutT>
__global__ __launch_bounds__(256) void sage_mfma(
        const _Float16* __restrict__ aggh, const _Float16* __restrict__ xh,
        const _Float16* __restrict__ Bswz, const float* __restrict__ bias,
        OutT* __restrict__ out, int N) {
    __shared__ _Float16 a_lds[128 * 132];

    const int tid = threadIdx.x;
    const int n0 = blockIdx.x * 128;
    const int wave = tid >> 6;
    const int lane = tid & 63;
    const int l31 = lane & 31;
    const int lhi = lane >> 5;

    floatx16 acc[4];
#pragma unroll
    for (int cb = 0; cb < 4; ++cb)
#pragma unroll
        for (int r = 0; r < 16; ++r) acc[cb][r] = 0.0f;

    const _Float16* ap = a_lds + (wave * 32 + l31) * 132 + lhi * 8;

#pragma unroll
    for (int phase = 0; phase < 2; ++phase) {
        const _Float16* src = phase ? xh : aggh;

        __syncthreads();
        {
            int r = tid >> 1;
            int p = tid & 1;
            _Float16* dstp = a_lds + r * 132 + p * 64;
            int gn = n0 + r;
            if (gn < N) {
                const float4* gp = (const float4*)(src + (size_t)gn * 128 + p * 64);
#pragma unroll
                for (int j = 0; j < 8; ++j) {
                    float4 v = gp[j];
                    float2* w2 = (float2*)(dstp + j * 8);
                    w2[0] = make_float2(v.x, v.y);
                    w2[1] = make_float2(v.z, v.w);
                }
            } else {
#pragma unroll
                for (int j = 0; j < 8; ++j) {
                    float2* w2 = (float2*)(dstp + j * 8);
                    w2[0] = make_float2(0.f, 0.f);
                    w2[1] = make_float2(0.f, 0.f);
                }
            }
        }
        __syncthreads();

        const _Float16* bbase = Bswz + ((size_t)phase * 8 * 4 * 512) + lane * 8;
#pragma unroll
        for (int ks = 0; ks < 8; ++ks) {
            half4v alo = *(const half4v*)(ap + ks * 16);
            half4v ahi = *(const half4v*)(ap + ks * 16 + 4);
            half8 afrag = __builtin_shufflevector(alo, ahi, 0, 1, 2, 3, 4, 5, 6, 7);
#pragma unroll
            for (int cb = 0; cb < 4; ++cb) {
                half8 bfrag = *(const half8*)(bbase + (ks * 4 + cb) * 512);
                acc[cb] = __builtin_amdgcn_mfma_f32_32x32x16_f16(
                    afrag, bfrag, acc[cb], 0, 0, 0);
            }
        }
    }

#pragma unroll
    for (int cb = 0; cb < 4; ++cb) {
        int col = cb * 32 + l31;
        float bv = bias[col];
#pragma unroll
        for (int r = 0; r < 16; ++r) {
            int rowin = (r & 3) + 8 * (r >> 2) + 4 * lhi;
            int grow = n0 + wave * 32 + rowin;
            if (grow < N) {
                float v = acc[cb][r] + bv;
                if (GELU) v = 0.5f * v * (1.0f + erff(v * 0.70710678118654752f));
                out[(size_t)grow * 128 + col] = (OutT)v;
            }
        }
    }
}

// ---------------------------------------------------------------------------
extern "C" void kernel_launch(void* const* d_in, const int* in_sizes, int n_in,
                              void* d_out, int out_size, void* d_ws, size_t ws_size,
                              hipStream_t stream) {
    const float* embs = (const float*)d_in[0];
    const int*   ei0  = (const int*)d_in[1];
    const int*   ei1  = (const int*)d_in[2];
    const float* w_l0 = (const float*)d_in[3];
    const float* w_r0 = (const float*)d_in[4];
    const float* b0   = (const float*)d_in[5];
    const float* w_l1 = (const float*)d_in[6];
    const float* w_r1 = (const float*)d_in[7];
    const float* b1   = (const float*)d_in[8];
    float* out = (float*)d_out;

    const int N = in_sizes[0] / D;
    const int E = in_sizes[1] / 2;
    const int nb = (N + SCAN_CHUNK - 1) / SCAN_CHUNK;   // <=256
    const int NB = (N + BW - 1) >> SH;                  // coarse buckets (13)

    // ws: x_h[ND] h_h[ND] agg_h[ND] Bswz0 Bswz1 (halfs) |
    //     rp0[N+1] rp1[N+1] cnt0[N] cnt1[N] es0[E] es1[E] blk_sums[512] gcur[512]
    // stage0/stage1 alias agg_h (dead during CSR build).
    _Float16* x_h   = (_Float16*)d_ws;
    _Float16* h_h   = x_h + (size_t)N * D;
    _Float16* agg_h = h_h + (size_t)N * D;
    _Float16* Bswz0 = agg_h + (size_t)N * D;
    _Float16* Bswz1 = Bswz0 + 64 * 512;
    int* rp0       = (int*)(Bswz1 + 64 * 512);
    int* rp1       = rp0 + (N + 1);
    int* cnt0      = rp1 + (N + 1);
    int* cnt1      = cnt0 + N;
    int* es0       = cnt1 + N;
    int* es1       = es0 + E;
    int* blk_sums  = es1 + E;
    int* gcur      = blk_sums + 512;
    int* stage0    = (int*)agg_h;       // alias: E ints each, 2E*4 <= N*D*2
    int* stage1    = stage0 + E;

    const int cast_grid  = ((size_t)N * D / 4 + 255) / 256;
    const int edge2_grid = (2 * E + 255) / 256;
    const int agg_grid   = ((size_t)N * 64 + 255) / 256;
    const int gemm_grid  = (N + 127) / 128;

    cast_half<<<cast_grid, 256, 0, stream>>>(embs, x_h, N * D);
    prep_bswz<<<128, 256, 0, stream>>>(w_l0, w_r0, Bswz0);
    prep_bswz<<<128, 256, 0, stream>>>(w_l1, w_r1, Bswz1);

    // ---- CSR build, both graphs ----
    hipMemsetAsync(cnt0, 0, (size_t)2 * N * sizeof(int), stream);
    hist2<<<edge2_grid, 256, 0, stream>>>(ei0, ei1, E, cnt0, cnt1);
    scan_phase_a<<<2 * nb, 256, 0, stream>>>(cnt0, cnt1, N, nb, blk_sums);
    scan_phase_b<<<2, 256, 0, stream>>>(blk_sums, nb);
    scan_phase_c<<<2 * nb, 256, 0, stream>>>(cnt0, cnt1, N, E, nb, blk_sums,
                                             rp0, rp1);
    gcur_init<<<1, 64, 0, stream>>>(rp0, rp1, N, gcur);
    bin_pass1<<<edge2_grid, 256, 0, stream>>>(ei0, ei1, E, gcur, stage0, stage1);
    bin_pass2<<<2 * NB, 256, 0, stream>>>(rp0, rp1, stage0, stage1,
                                          es0, es1, N, NB);

    // ---- layer 0 ----
    agg_half<<<agg_grid, 256, 0, stream>>>(x_h, rp0, es0, agg_h, N);
    sage_mfma<true, _Float16><<<gemm_grid, 256, 0, stream>>>(
        agg_h, x_h, Bswz0, b0, h_h, N);

    // ---- layer 1 ----
    agg_half<<<agg_grid, 256, 0, stream>>>(h_h, rp1, es1, agg_h, N);
    sage_mfma<false, float><<<gemm_grid, 256, 0, stream>>>(
        agg_h, h_h, Bswz1, b1, out, N);
}

// Round 6
// 435.313 us; speedup vs baseline: 1.9242x; 1.9242x over previous
//
#include <hip/hip_runtime.h>
#include <hip/hip_fp16.h>
#include <math.h>

#define D 128
#define SH 9               // fine bucket shift: 512 dsts per bucket
#define BW (1 << SH)
#define EPT 16             // edges per thread in binning kernels

typedef _Float16 half4v __attribute__((ext_vector_type(4)));
typedef _Float16 half8  __attribute__((ext_vector_type(8)));
typedef float    floatx16 __attribute__((ext_vector_type(16)));

// ---------------------------------------------------------------------------
// Cast fp32 -> fp16 (4 elems/thread).
// ---------------------------------------------------------------------------
__global__ __launch_bounds__(256) void cast_half(
        const float* __restrict__ x, _Float16* __restrict__ y, int n) {
    int i = blockIdx.x * 256 + threadIdx.x;
    int idx = i * 4;
    if (idx >= n) return;
    float4 v = *(const float4*)(x + idx);
    half4v h;
    h[0] = (_Float16)v.x; h[1] = (_Float16)v.y;
    h[2] = (_Float16)v.z; h[3] = (_Float16)v.w;
    *(half4v*)(y + idx) = h;
}

// ---------------------------------------------------------------------------
// Build B fragments pre-swizzled for v_mfma_f32_32x32x16_f16.
// WT[k][c] = (k<128) ? w_l[c][k] : w_r[c][k-128], k in [0,256).
// Fragment f = ks*4+cb, lane l, elem j:
//   value = WT[ks*16 + (l>>5)*8 + j][cb*32 + (l&31)] at B[f*512 + l*8 + j].
// ---------------------------------------------------------------------------
__global__ __launch_bounds__(256) void prep_bswz(
        const float* __restrict__ wl, const float* __restrict__ wr,
        _Float16* __restrict__ B) {
    int idx = blockIdx.x * 256 + threadIdx.x;  // 64*512 = 32768
    if (idx >= 64 * 512) return;
    int j = idx & 7;
    int lane = (idx >> 3) & 63;
    int f = idx >> 9;
    int ks = f >> 2, cb = f & 3;
    int k = ks * 16 + (lane >> 5) * 8 + j;
    int c = cb * 32 + (lane & 31);
    float v = (k < 128) ? wl[c * 128 + k] : wr[c * 128 + (k - 128)];
    B[idx] = (_Float16)v;
}

// ---------------------------------------------------------------------------
// Coarse histogram: per (graph, fine-bucket) edge counts. LDS hist per block,
// one global atomic per nonzero bin per block (line-padded ccnt[b*16]).
// ---------------------------------------------------------------------------
__global__ __launch_bounds__(256) void hist_coarse(
        const int* __restrict__ ei0, const int* __restrict__ ei1,
        int E, int NBK, int* __restrict__ ccnt) {
    __shared__ int h[512];
    int NBIN = 2 * NBK;
    int t = threadIdx.x;
    h[t] = 0; h[t + 256] = 0;
    __syncthreads();
    int t0 = blockIdx.x * (256 * EPT) + t;
#pragma unroll
    for (int k = 0; k < EPT; ++k) {
        int idx = t0 + k * 256;
        if (idx < 2 * E) {
            int g = idx >= E;
            int e = idx - g * E;
            int dst = (g ? ei1 : ei0)[E + e];
            atomicAdd(&h[g * NBK + (dst >> SH)], 1);
        }
    }
    __syncthreads();
    for (int b = t; b < NBIN; b += 256)
        if (h[b]) atomicAdd(&ccnt[b * 16], h[b]);
}

// ---------------------------------------------------------------------------
// Coarse scan: one block; per-graph exclusive prefix over NBK bin counts.
// Writes gbase[b] (bucket start in stage/es space) and inits gcur[b*16].
// Also writes rp0[N]=rp1[N]=E.
// ---------------------------------------------------------------------------
__global__ __launch_bounds__(256) void scan_coarse(
        const int* __restrict__ ccnt, int NBK, int E, int N,
        int* __restrict__ gbase, int* __restrict__ gcur,
        int* __restrict__ rp0, int* __restrict__ rp1) {
    __shared__ int part[256];
    int t = threadIdx.x;
    for (int g = 0; g < 2; ++g) {
        int v = (t < NBK) ? ccnt[(g * NBK + t) * 16] : 0;
        part[t] = v;
        __syncthreads();
        for (int off = 1; off < 256; off <<= 1) {
            int u = (t >= off) ? part[t - off] : 0;
            __syncthreads();
            part[t] += u;
            __syncthreads();
        }
        if (t < NBK) {
            int ex = (t == 0) ? 0 : part[t - 1];
            int b = g * NBK + t;
            gbase[b] = ex;
            gcur[b * 16] = ex;
        }
        __syncthreads();
    }
    if (t == 0) { rp0[N] = E; rp1[N] = E; }
}

// ---------------------------------------------------------------------------
// Multisplit pass 1: bin edges into fine buckets. 4096 edges/block.
// LDS histogram -> one global reserve atomic per (block,bin) -> LDS-rank
// scatter of packed (src | dstlow<<17) into the per-graph stage array.
// ---------------------------------------------------------------------------
__global__ __launch_bounds__(256) void bin_pass1(
        const int* __restrict__ ei0, const int* __restrict__ ei1,
        int E, int NBK, int* __restrict__ gcur,
        int* __restrict__ stage0, int* __restrict__ stage1) {
    __shared__ int cnt[512];
    __shared__ int base[512];
    int NBIN = 2 * NBK;
    int t = threadIdx.x;
    cnt[t] = 0; cnt[t + 256] = 0;
    __syncthreads();
    int t0 = blockIdx.x * (256 * EPT) + t;
    int pk[EPT];
    int bn[EPT];
#pragma unroll
    for (int k = 0; k < EPT; ++k) {
        int idx = t0 + k * 256;
        bn[k] = -1;
        if (idx < 2 * E) {
            int g = idx >= E;
            int e = idx - g * E;
            const int* ei = g ? ei1 : ei0;
            int src = ei[e];
            int dst = ei[E + e];
            pk[k] = src | ((dst & (BW - 1)) << 17);
            bn[k] = g * NBK + (dst >> SH);
            atomicAdd(&cnt[bn[k]], 1);
        }
    }
    __syncthreads();
    for (int b = t; b < NBIN; b += 256) {
        int c = cnt[b];
        base[b] = c ? atomicAdd(&gcur[b * 16], c) : 0;
        cnt[b] = 0;  // reuse as rank counter
    }
    __syncthreads();
#pragma unroll
    for (int k = 0; k < EPT; ++k) {
        if (bn[k] >= 0) {
            int b = bn[k];
            int r = atomicAdd(&cnt[b], 1);
            int* stage = (b >= NBK) ? stage1 : stage0;
            stage[base[b] + r] = pk[k];
        }
    }
}

// ---------------------------------------------------------------------------
// Multisplit pass 2: one block per fine bucket (2*NBK blocks).
// Counts its 512 dsts in LDS, in-block scan -> writes row_ptr slice and LDS
// cursors, then scatters srcs into final CSR slots. All es writes for this
// ~32 KB region come from ONE block -> L2 merges to full lines.
// ---------------------------------------------------------------------------
__global__ __launch_bounds__(256) void bin_pass2(
        const int* __restrict__ gbase,
        const int* __restrict__ stage0, const int* __restrict__ stage1,
        int* __restrict__ rp0, int* __restrict__ rp1,
        int* __restrict__ es0, int* __restrict__ es1,
        int N, int NBK, int E) {
    __shared__ int cnt[BW];
    __shared__ int part[256];
    int b = blockIdx.x;
    int g = b >= NBK;
    int bk = b - g * NBK;
    const int* stage = g ? stage1 : stage0;
    int* rp = g ? rp1 : rp0;
    int* es = g ? es1 : es0;
    int lo = bk << SH;
    int hi = min(lo + BW, N);
    int nd = hi - lo;
    int beg = gbase[b];
    int end = (bk == NBK - 1) ? E : gbase[b + 1];
    int t = threadIdx.x;
    cnt[t] = 0; cnt[t + 256] = 0;
    __syncthreads();
    for (int i = beg + t; i < end; i += 256)
        atomicAdd(&cnt[(unsigned)stage[i] >> 17], 1);
    __syncthreads();
    int c0 = cnt[t * 2], c1 = cnt[t * 2 + 1];
    part[t] = c0 + c1;
    __syncthreads();
    for (int off = 1; off < 256; off <<= 1) {
        int u = (t >= off) ? part[t - off] : 0;
        __syncthreads();
        part[t] += u;
        __syncthreads();
    }
    int ex = (t == 0) ? 0 : part[t - 1];
    int base0 = beg + ex;
    if (t * 2 < nd)     rp[lo + t * 2]     = base0;
    if (t * 2 + 1 < nd) rp[lo + t * 2 + 1] = base0 + c0;
    __syncthreads();               // all reads of cnt done (scan barriers passed)
    cnt[t * 2] = base0;
    cnt[t * 2 + 1] = base0 + c0;
    __syncthreads();
    int i = beg + t;
    for (; i + 768 < end; i += 1024) {
        unsigned p0 = (unsigned)stage[i];
        unsigned p1 = (unsigned)stage[i + 256];
        unsigned p2 = (unsigned)stage[i + 512];
        unsigned p3 = (unsigned)stage[i + 768];
        int q0 = atomicAdd(&cnt[p0 >> 17], 1);
        int q1 = atomicAdd(&cnt[p1 >> 17], 1);
        int q2 = atomicAdd(&cnt[p2 >> 17], 1);
        int q3 = atomicAdd(&cnt[p3 >> 17], 1);
        es[q0] = p0 & 0x1FFFF;
        es[q1] = p1 & 0x1FFFF;
        es[q2] = p2 & 0x1FFFF;
        es[q3] = p3 & 0x1FFFF;
    }
    for (; i < end; i += 256) {
        unsigned p = (unsigned)stage[i];
        int q = atomicAdd(&cnt[p >> 17], 1);
        es[q] = p & 0x1FFFF;
    }
}

// ---------------------------------------------------------------------------
// Gather aggregation in fp16: one wave per node, lane holds a half2 (2 dims).
// 8-deep MLP unroll; fp32 accumulation, fp16 output.
// ---------------------------------------------------------------------------
__global__ __launch_bounds__(256) void agg_half(
        const _Float16* __restrict__ x, const int* __restrict__ row_ptr,
        const int* __restrict__ edge_src, _Float16* __restrict__ agg, int N) {
    int gt = blockIdx.x * 256 + threadIdx.x;
    int w = gt >> 6;
    int lane = gt & 63;
    if (w >= N) return;
    int beg = row_ptr[w];
    int end = row_ptr[w + 1];
    const __half2* base = (const __half2*)x + lane;
    float ax = 0.0f, ay = 0.0f;
    int e = beg;
    for (; e + 8 <= end; e += 8) {
        int s[8];
#pragma unroll
        for (int j = 0; j < 8; ++j) s[j] = edge_src[e + j];
#pragma unroll
        for (int j = 0; j < 8; ++j) {
            float2 f = __half22float2(base[(size_t)s[j] * 64]);
            ax += f.x;
            ay += f.y;
        }
    }
    for (; e < end; ++e) {
        float2 f = __half22float2(base[(size_t)edge_src[e] * 64]);
        ax += f.x;
        ay += f.y;
    }
    int deg = end - beg;
    float inv = (deg > 0) ? 1.0f / (float)deg : 0.0f;
    ((__half2*)agg)[(size_t)w * 64 + lane] =
        __float22half2_rn(make_float2(ax * inv, ay * inv));
}

// ---------------------------------------------------------------------------
// MFMA SAGE linear (validated in round 4).
// ---------------------------------------------------------------------------
template <bool GELU, typename OutT>
__global__ __launch_bounds__(256) void sage_mfma(
        const _Float16* __restrict__ aggh, const _Float16* __restrict__ xh,
        const _Float16* __restrict__ Bswz, const float* __restrict__ bias,
        OutT* __restrict__ out, int N) {
    __shared__ _Float16 a_lds[128 * 132];

    const int tid = threadIdx.x;
    const int n0 = blockIdx.x * 128;
    const int wave = tid >> 6;
    const int lane = tid & 63;
    const int l31 = lane & 31;
    const int lhi = lane >> 5;

    floatx16 acc[4];
#pragma unroll
    for (int cb = 0; cb < 4; ++cb)
#pragma unroll
        for (int r = 0; r < 16; ++r) acc[cb][r] = 0.0f;

    const _Float16* ap = a_lds + (wave * 32 + l31) * 132 + lhi * 8;

#pragma unroll
    for (int phase = 0; phase < 2; ++phase) {
        const _Float16* src = phase ? xh : aggh;

        __syncthreads();
        {
            int r = tid >> 1;
            int p = tid & 1;
            _Float16* dstp = a_lds + r * 132 + p * 64;
            int gn = n0 + r;
            if (gn < N) {
                const float4* gp = (const float4*)(src + (size_t)gn * 128 + p * 64);
#pragma unroll
                for (int j = 0; j < 8; ++j) {
                    float4 v = gp[j];
                    float2* w2 = (float2*)(dstp + j * 8);
                    w2[0] = make_float2(v.x, v.y);
                    w2[1] = make_float2(v.z, v.w);
                }
            } else {
#pragma unroll
                for (int j = 0; j < 8; ++j) {
                    float2* w2 = (float2*)(dstp + j * 8);
                    w2[0] = make_float2(0.f, 0.f);
                    w2[1] = make_float2(0.f, 0.f);
                }
            }
        }
        __syncthreads();

        const _Float16* bbase = Bswz + ((size_t)phase * 8 * 4 * 512) + lane * 8;
#pragma unroll
        for (int ks = 0; ks < 8; ++ks) {
            half4v alo = *(const half4v*)(ap + ks * 16);
            half4v ahi = *(const half4v*)(ap + ks * 16 + 4);
            half8 afrag = __builtin_shufflevector(alo, ahi, 0, 1, 2, 3, 4, 5, 6, 7);
#pragma unroll
            for (int cb = 0; cb < 4; ++cb) {
                half8 bfrag = *(const half8*)(bbase + (ks * 4 + cb) * 512);
                acc[cb] = __builtin_amdgcn_mfma_f32_32x32x16_f16(
                    afrag, bfrag, acc[cb], 0, 0, 0);
            }
        }
    }

#pragma unroll
    for (int cb = 0; cb < 4; ++cb) {
        int col = cb * 32 + l31;
        float bv = bias[col];
#pragma unroll
        for (int r = 0; r < 16; ++r) {
            int rowin = (r & 3) + 8 * (r >> 2) + 4 * lhi;
            int grow = n0 + wave * 32 + rowin;
            if (grow < N) {
                float v = acc[cb][r] + bv;
                if (GELU) v = 0.5f * v * (1.0f + erff(v * 0.70710678118654752f));
                out[(size_t)grow * 128 + col] = (OutT)v;
            }
        }
    }
}

// ---------------------------------------------------------------------------
extern "C" void kernel_launch(void* const* d_in, const int* in_sizes, int n_in,
                              void* d_out, int out_size, void* d_ws, size_t ws_size,
                              hipStream_t stream) {
    const float* embs = (const float*)d_in[0];
    const int*   ei0  = (const int*)d_in[1];
    const int*   ei1  = (const int*)d_in[2];
    const float* w_l0 = (const float*)d_in[3];
    const float* w_r0 = (const float*)d_in[4];
    const float* b0   = (const float*)d_in[5];
    const float* w_l1 = (const float*)d_in[6];
    const float* w_r1 = (const float*)d_in[7];
    const float* b1   = (const float*)d_in[8];
    float* out = (float*)d_out;

    const int N = in_sizes[0] / D;
    const int E = in_sizes[1] / 2;
    const int NBK = (N + BW - 1) >> SH;      // fine buckets per graph (196)
    const int NBIN = 2 * NBK;                // must be <= 512

    // ws: x_h[ND] h_h[ND] agg_h[ND] Bswz0 Bswz1 (halfs) |
    //     rp0[N+1] rp1[N+1] es0[E] es1[E] ccnt[NBIN*16] gbase[NBIN] gcur[NBIN*16]
    // stage0/stage1 alias agg_h (dead during CSR build; 2E*4 <= N*D*2 bytes).
    _Float16* x_h   = (_Float16*)d_ws;
    _Float16* h_h   = x_h + (size_t)N * D;
    _Float16* agg_h = h_h + (size_t)N * D;
    _Float16* Bswz0 = agg_h + (size_t)N * D;
    _Float16* Bswz1 = Bswz0 + 64 * 512;
    int* rp0   = (int*)(Bswz1 + 64 * 512);
    int* rp1   = rp0 + (N + 1);
    int* es0   = rp1 + (N + 1);
    int* es1   = es0 + E;
    int* ccnt  = es1 + E;
    int* gbase = ccnt + NBIN * 16;
    int* gcur  = gbase + NBIN;
    int* stage0 = (int*)agg_h;
    int* stage1 = stage0 + E;

    const int cast_grid = ((size_t)N * D / 4 + 255) / 256;
    const int bin_grid  = (2 * E + 256 * EPT - 1) / (256 * EPT);
    const int agg_grid  = ((size_t)N * 64 + 255) / 256;
    const int gemm_grid = (N + 127) / 128;

    cast_half<<<cast_grid, 256, 0, stream>>>(embs, x_h, N * D);
    prep_bswz<<<128, 256, 0, stream>>>(w_l0, w_r0, Bswz0);
    prep_bswz<<<128, 256, 0, stream>>>(w_l1, w_r1, Bswz1);

    // ---- CSR build, both graphs ----
    hipMemsetAsync(ccnt, 0, (size_t)NBIN * 16 * sizeof(int), stream);
    hist_coarse<<<bin_grid, 256, 0, stream>>>(ei0, ei1, E, NBK, ccnt);
    scan_coarse<<<1, 256, 0, stream>>>(ccnt, NBK, E, N, gbase, gcur, rp0, rp1);
    bin_pass1<<<bin_grid, 256, 0, stream>>>(ei0, ei1, E, NBK, gcur,
                                            stage0, stage1);
    bin_pass2<<<NBIN, 256, 0, stream>>>(gbase, stage0, stage1,
                                        rp0, rp1, es0, es1, N, NBK, E);

    // ---- layer 0 ----
    agg_half<<<agg_grid, 256, 0, stream>>>(x_h, rp0, es0, agg_h, N);
    sage_mfma<true, _Float16><<<gemm_grid, 256, 0, stream>>>(
        agg_h, x_h, Bswz0, b0, h_h, N);

    // ---- layer 1 ----
    agg_half<<<agg_grid, 256, 0, stream>>>(h_h, rp1, es1, agg_h, N);
    sage_mfma<false, float><<<gemm_grid, 256, 0, stream>>>(
        agg_h, h_h, Bswz1, b1, out, N);
}